// Round 7
// baseline (754.569 us; speedup 1.0000x reference)
//
#include <hip/hip_runtime.h>
#include <math.h>

#define D_MODEL 1024
#define N_HEADS 16
#define D_HEAD  64
#define LSR_RANK 32
#define BATCH 2
#define SEQ 2048
#define M_TOT (BATCH*SEQ)          // 4096 rows (B*T)
#define NCAT  2048                 // q_lr(512) | k_lr(512) | v(1024)

// ---------------------------------------------------------------------------
// Weff[k, h*32+r] = sum_d W[k, h*64+d] * Wlsr[h, d, r]
// ---------------------------------------------------------------------------
__global__ __launch_bounds__(256) void eff_weight_kernel(
    const float* __restrict__ W, const float* __restrict__ Wlsr,
    float* __restrict__ Weff)
{
    int idx = blockIdx.x * 256 + threadIdx.x;     // 1024*512 outputs
    int k = idx >> 9;
    int c = idx & 511;
    int h = c >> 5;
    int r = c & 31;
    const float* wrow = W + (size_t)k * D_MODEL + h * D_HEAD;
    const float* lsr  = Wlsr + (size_t)h * D_HEAD * LSR_RANK + r;
    float acc = 0.f;
    #pragma unroll
    for (int d = 0; d < D_HEAD; ++d)
        acc = fmaf(wrow[d], lsr[d * LSR_RANK], acc);
    Weff[(size_t)k * (N_HEADS * LSR_RANK) + c] = acc;
}

__global__ void eff_bias_kernel(const float* __restrict__ bias,
                                const float* __restrict__ Wlsr,
                                float* __restrict__ beff)
{
    int c = threadIdx.x;   // 512
    int h = c >> 5, r = c & 31;
    float acc = 0.f;
    #pragma unroll
    for (int d = 0; d < D_HEAD; ++d)
        acc = fmaf(bias[h * D_HEAD + d],
                   Wlsr[(size_t)h * D_HEAD * LSR_RANK + d * LSR_RANK + r], acc);
    beff[c] = acc;
}

// ---------------------------------------------------------------------------
// fp32 GEMM tile: 64 (M) x 128 (N), BK=16, 256 threads, 4x8 micro-tile.
// ---------------------------------------------------------------------------
__device__ __forceinline__ void gemm_tile_64x128(
    const float* __restrict__ A, int lda,
    const float* __restrict__ B, int ldb,
    const float* __restrict__ bias,
    float* __restrict__ C, int ldc)
{
    __shared__ float As[16][68];
    __shared__ float Bs[16][136];

    const int tid = threadIdx.x;
    const int tx = tid & 15;
    const int ty = tid >> 4;
    const int arow = tid >> 2;
    const int akq  = tid & 3;
    const int bn4  = tid & 31;
    const int bk   = tid >> 5;

    float acc[4][8];
    #pragma unroll
    for (int i = 0; i < 4; ++i)
        #pragma unroll
        for (int j = 0; j < 8; ++j) acc[i][j] = 0.f;

    for (int k0 = 0; k0 < D_MODEL; k0 += 16) {
        float4 av = *(const float4*)&A[(size_t)arow * lda + k0 + akq * 4];
        As[akq*4+0][arow] = av.x;
        As[akq*4+1][arow] = av.y;
        As[akq*4+2][arow] = av.z;
        As[akq*4+3][arow] = av.w;
        #pragma unroll
        for (int p = 0; p < 2; ++p) {
            int k = bk + p * 8;
            *(float4*)&Bs[k][bn4 * 4] =
                *(const float4*)&B[(size_t)(k0 + k) * ldb + bn4 * 4];
        }
        __syncthreads();
        #pragma unroll
        for (int kk = 0; kk < 16; ++kk) {
            float4 a  = *(const float4*)&As[kk][ty * 4];
            float4 b0 = *(const float4*)&Bs[kk][tx * 8];
            float4 b1 = *(const float4*)&Bs[kk][tx * 8 + 4];
            float avv[4] = {a.x, a.y, a.z, a.w};
            float bvv[8] = {b0.x, b0.y, b0.z, b0.w, b1.x, b1.y, b1.z, b1.w};
            #pragma unroll
            for (int i = 0; i < 4; ++i)
                #pragma unroll
                for (int j = 0; j < 8; ++j)
                    acc[i][j] = fmaf(avv[i], bvv[j], acc[i][j]);
        }
        __syncthreads();
    }
    #pragma unroll
    for (int i = 0; i < 4; ++i) {
        #pragma unroll
        for (int j = 0; j < 8; ++j) {
            C[(size_t)(ty * 4 + i) * ldc + tx * 8 + j] =
                acc[i][j] + bias[tx * 8 + j];
        }
    }
}

__global__ __launch_bounds__(256) void proj_kernel(
    const float* __restrict__ x,
    const float* __restrict__ Wq_eff, const float* __restrict__ Wk_eff,
    const float* __restrict__ Wv,
    const float* __restrict__ bq_eff, const float* __restrict__ bk_eff,
    const float* __restrict__ bv,
    float* __restrict__ Y)
{
    int n0 = blockIdx.x * 128;
    int m0 = blockIdx.y * 64;
    const float* B; const float* bias; int ldb;
    if (n0 < 512)       { B = Wq_eff + n0;          bias = bq_eff + n0;          ldb = 512;  }
    else if (n0 < 1024) { B = Wk_eff + (n0 - 512);  bias = bk_eff + (n0 - 512);  ldb = 512;  }
    else                { B = Wv + (n0 - 1024);     bias = bv + (n0 - 1024);     ldb = 1024; }
    gemm_tile_64x128(x + (size_t)m0 * D_MODEL, D_MODEL, B, ldb, bias,
                     Y + (size_t)m0 * NCAT + n0, NCAT);
}

__global__ __launch_bounds__(256) void out_kernel(
    const float* __restrict__ O, const float* __restrict__ Wo,
    const float* __restrict__ bo, float* __restrict__ out)
{
    int n0 = blockIdx.x * 128;
    int m0 = blockIdx.y * 64;
    gemm_tile_64x128(O + (size_t)m0 * D_MODEL, D_MODEL, Wo + n0, D_MODEL,
                     bo + n0, out + (size_t)m0 * D_MODEL + n0, D_MODEL);
}

// ---------------------------------------------------------------------------
// Flash attention, v5: uniform blocks + 4 blocks/CU sustained.
// Round-6 diagnosis: 313 us at Occupancy 22%, VALUBusy 55% -- grid of 1024
// variable-length blocks (runtime ~ qt+1) all resident at t=0, then drain:
// resident waves decay 16 -> 4, no refill. Fix: make every block identical.
//   block = (bh, pq, half): processes 32 q-rows (half of a q-tile) for BOTH
//   qt = pq and qt = 31-pq  => exactly 33 KV-tile iters per block, uniform.
//   grid 32 x 16 x 2 = 1024 blocks, 4/CU co-resident the whole time.
// Thread (row = tid&31, oct = tid>>5): oct owns 8 KV cols; s[16] -> s[8]
// shrinks live range; __launch_bounds__(256,4) caps VGPR at 128 => 16
// waves/CU. Epilogue keeps v4's literal-index rule (o[] never runtime-
// indexed; `oct == st` predication leaves indices compile-time).
// ---------------------------------------------------------------------------
#define SK_LD 36
#define SV_LD 68
#define MASKVAL (-1e30f)

__global__ __launch_bounds__(256, 4) void flash_kernel(
    const float* __restrict__ Y,   // (4096, 2048): q_lr | k_lr | v
    float* __restrict__ O)         // (4096, 1024): (B,T,H,Dh)
{
    const float scale = 0.1767766952966369f;  // 1/sqrt(32)
    const int bh  = blockIdx.x;
    const int pq  = blockIdx.y;                // 0..15
    const int hlf = blockIdx.z;                // 0..1: which 32-row half
    const int b = bh >> 4, h = bh & 15;
    const int tid = threadIdx.x;
    const int row = tid & 31;                  // 0..31
    const int oct = tid >> 5;                  // 0..7, owns 8 kv cols

    __shared__ float smem[64 * SK_LD + 64 * SV_LD];  // sk | sv; reused as accum
    __shared__ float sml[2][8][32];                  // m, l per (oct,row)
    float* sk = smem;                 // [64][SK_LD]
    float* sv = smem + 64 * SK_LD;    // [64][SV_LD]
    float* accum = smem;              // [32][65] after main loop

    #pragma unroll 1
    for (int pass = 0; pass < 2; ++pass) {
        const int qt = pass ? (31 - pq) : pq;
        const int t = qt * 64 + hlf * 32 + row;

        // load q_lr row into registers
        float q[32];
        {
            const float* qrow = Y + (size_t)(b * SEQ + t) * NCAT + h * 32;
            #pragma unroll
            for (int r4 = 0; r4 < 8; ++r4) {
                float4 f = ((const float4*)qrow)[r4];
                q[r4*4+0] = f.x; q[r4*4+1] = f.y; q[r4*4+2] = f.z; q[r4*4+3] = f.w;
            }
        }
        float o[64];
        #pragma unroll
        for (int d = 0; d < 64; ++d) o[d] = 0.f;
        float mrun = MASKVAL, lrun = 0.f;

        for (int jt = 0; jt <= qt; ++jt) {
            // cooperative tile load: 256 threads, 64 kv rows, 4 loaders/row
            {
                const int r  = tid >> 2;
                const int sg = tid & 3;
                const size_t rb = (size_t)(b * SEQ + jt * 64 + r) * NCAT;
                const float* krow = Y + rb + 512 + h * 32;
                const float* vrow = Y + rb + 1024 + h * 64;
                *(float4*)&sk[r * SK_LD + sg * 8]     = ((const float4*)krow)[sg*2];
                *(float4*)&sk[r * SK_LD + sg * 8 + 4] = ((const float4*)krow)[sg*2+1];
                #pragma unroll
                for (int p = 0; p < 4; ++p)
                    *(float4*)&sv[r * SV_LD + sg * 16 + p * 4] =
                        ((const float4*)vrow)[sg * 4 + p];
            }
            __syncthreads();

            // scores for this oct's 8 kv columns (float4 broadcast reads)
            float s[8];
            float mt = MASKVAL;
            #pragma unroll
            for (int jj = 0; jj < 8; ++jj) {
                const int j = oct * 8 + jj;
                const float4* kr = (const float4*)&sk[j * SK_LD];
                float acc = 0.f;
                #pragma unroll
                for (int r4 = 0; r4 < 8; ++r4) {
                    float4 kv = kr[r4];
                    acc = fmaf(q[r4*4+0], kv.x, acc);
                    acc = fmaf(q[r4*4+1], kv.y, acc);
                    acc = fmaf(q[r4*4+2], kv.z, acc);
                    acc = fmaf(q[r4*4+3], kv.w, acc);
                }
                acc *= scale;
                const int gj = jt * 64 + j;
                acc = (gj <= t) ? acc : MASKVAL;
                s[jj] = acc;
                mt = fmaxf(mt, acc);
            }
            const float mnew = fmaxf(mrun, mt);
            const float alpha = expf(mrun - mnew);
            float psum = 0.f;
            #pragma unroll
            for (int jj = 0; jj < 8; ++jj) {
                float p = expf(s[jj] - mnew);
                s[jj] = p;
                psum += p;
            }
            lrun = lrun * alpha + psum;
            #pragma unroll
            for (int d = 0; d < 64; ++d) o[d] *= alpha;
            #pragma unroll
            for (int jj = 0; jj < 8; ++jj) {
                const int j = oct * 8 + jj;
                const float p = s[jj];
                const float4* vr = (const float4*)&sv[j * SV_LD];
                #pragma unroll
                for (int d4 = 0; d4 < 16; ++d4) {
                    float4 vv = vr[d4];
                    o[d4*4+0] = fmaf(p, vv.x, o[d4*4+0]);
                    o[d4*4+1] = fmaf(p, vv.y, o[d4*4+1]);
                    o[d4*4+2] = fmaf(p, vv.z, o[d4*4+2]);
                    o[d4*4+3] = fmaf(p, vv.w, o[d4*4+3]);
                }
            }
            mrun = mnew;
            __syncthreads();
        }

        // combine the 8 oct-partials of each row
        sml[0][oct][row] = mrun;
        sml[1][oct][row] = lrun;
        __syncthreads();
        float mg = MASKVAL;
        #pragma unroll
        for (int qq = 0; qq < 8; ++qq) mg = fmaxf(mg, sml[0][qq][row]);
        float lg = 0.f;
        #pragma unroll
        for (int qq = 0; qq < 8; ++qq)
            lg += sml[1][qq][row] * expf(sml[0][qq][row] - mg);
        const float alpha = expf(mrun - mg);   // 0 for never-valid octs

        // serialized combine: literal o[] indices only (rule #20); the
        // `oct == st` predicate leaves o[] fully register-allocated.
        #pragma unroll
        for (int st = 0; st < 8; ++st) {
            if (oct == st) {
                if (st == 0) {
                    #pragma unroll
                    for (int dd = 0; dd < 64; ++dd)
                        accum[row * 65 + dd] = alpha * o[dd];
                } else {
                    #pragma unroll
                    for (int dd = 0; dd < 64; ++dd)
                        accum[row * 65 + dd] += alpha * o[dd];
                }
            }
            __syncthreads();
        }

        // write output: thread (row, oct) writes 8 contiguous floats
        {
            const float inv = 1.f / lg;
            float* orow = O + (size_t)(b * SEQ + t) * D_MODEL + h * D_HEAD;
            #pragma unroll
            for (int dd = 0; dd < 8; ++dd)
                orow[oct * 8 + dd] =
                    accum[row * 65 + oct * 8 + dd] * inv;
        }
        __syncthreads();   // smem (accum) reused as sk/sv by next pass
    }
}

// ---------------------------------------------------------------------------
extern "C" void kernel_launch(void* const* d_in, const int* in_sizes, int n_in,
                              void* d_out, int out_size, void* d_ws, size_t ws_size,
                              hipStream_t stream)
{
    const float* x      = (const float*)d_in[0];
    const float* Wq     = (const float*)d_in[1];
    const float* bq     = (const float*)d_in[2];
    const float* Wk     = (const float*)d_in[3];
    const float* bk     = (const float*)d_in[4];
    const float* Wv     = (const float*)d_in[5];
    const float* bv     = (const float*)d_in[6];
    const float* Wo     = (const float*)d_in[7];
    const float* bo     = (const float*)d_in[8];
    const float* Wq_lsr = (const float*)d_in[9];
    const float* Wk_lsr = (const float*)d_in[10];
    float* out = (float*)d_out;

    float* ws      = (float*)d_ws;
    float* Wq_eff  = ws;                               // 1024*512
    float* Wk_eff  = Wq_eff + 1024 * 512;              // 1024*512
    float* bq_eff  = Wk_eff + 1024 * 512;              // 512
    float* bk_eff  = bq_eff + 512;                     // 512
    float* Ycat    = bk_eff + 512;                     // 4096*2048
    float* Oacc    = Ycat + (size_t)M_TOT * NCAT;      // 4096*1024

    eff_weight_kernel<<<2048, 256, 0, stream>>>(Wq, Wq_lsr, Wq_eff);
    eff_weight_kernel<<<2048, 256, 0, stream>>>(Wk, Wk_lsr, Wk_eff);
    eff_bias_kernel<<<1, 512, 0, stream>>>(bq, Wq_lsr, bq_eff);
    eff_bias_kernel<<<1, 512, 0, stream>>>(bk, Wk_lsr, bk_eff);

    proj_kernel<<<dim3(NCAT / 128, M_TOT / 64), 256, 0, stream>>>(
        x, Wq_eff, Wk_eff, Wv, bq_eff, bk_eff, bv, Ycat);

    flash_kernel<<<dim3(BATCH * N_HEADS, 16, 2), 256, 0, stream>>>(Ycat, Oacc);

    out_kernel<<<dim3(D_MODEL / 128, M_TOT / 64), 256, 0, stream>>>(
        Oacc, Wo, bo, out);
}

// Round 8
// 676.806 us; speedup vs baseline: 1.1149x; 1.1149x over previous
//
#include <hip/hip_runtime.h>
#include <math.h>

#define D_MODEL 1024
#define N_HEADS 16
#define D_HEAD  64
#define LSR_RANK 32
#define BATCH 2
#define SEQ 2048
#define M_TOT (BATCH*SEQ)          // 4096 rows (B*T)
#define NCAT  2048                 // q_lr(512) | k_lr(512) | v(1024)

// ---------------------------------------------------------------------------
// Weff[k, h*32+r] = sum_d W[k, h*64+d] * Wlsr[h, d, r]
// ---------------------------------------------------------------------------
__global__ __launch_bounds__(256) void eff_weight_kernel(
    const float* __restrict__ W, const float* __restrict__ Wlsr,
    float* __restrict__ Weff)
{
    int idx = blockIdx.x * 256 + threadIdx.x;     // 1024*512 outputs
    int k = idx >> 9;
    int c = idx & 511;
    int h = c >> 5;
    int r = c & 31;
    const float* wrow = W + (size_t)k * D_MODEL + h * D_HEAD;
    const float* lsr  = Wlsr + (size_t)h * D_HEAD * LSR_RANK + r;
    float acc = 0.f;
    #pragma unroll
    for (int d = 0; d < D_HEAD; ++d)
        acc = fmaf(wrow[d], lsr[d * LSR_RANK], acc);
    Weff[(size_t)k * (N_HEADS * LSR_RANK) + c] = acc;
}

__global__ void eff_bias_kernel(const float* __restrict__ bias,
                                const float* __restrict__ Wlsr,
                                float* __restrict__ beff)
{
    int c = threadIdx.x;   // 512
    int h = c >> 5, r = c & 31;
    float acc = 0.f;
    #pragma unroll
    for (int d = 0; d < D_HEAD; ++d)
        acc = fmaf(bias[h * D_HEAD + d],
                   Wlsr[(size_t)h * D_HEAD * LSR_RANK + d * LSR_RANK + r], acc);
    beff[c] = acc;
}

// ---------------------------------------------------------------------------
// fp32 GEMM tile: 64 (M) x 128 (N), BK=16, 256 threads, 4x8 micro-tile.
// ---------------------------------------------------------------------------
__device__ __forceinline__ void gemm_tile_64x128(
    const float* __restrict__ A, int lda,
    const float* __restrict__ B, int ldb,
    const float* __restrict__ bias,
    float* __restrict__ C, int ldc)
{
    __shared__ float As[16][68];
    __shared__ float Bs[16][136];

    const int tid = threadIdx.x;
    const int tx = tid & 15;
    const int ty = tid >> 4;
    const int arow = tid >> 2;
    const int akq  = tid & 3;
    const int bn4  = tid & 31;
    const int bk   = tid >> 5;

    float acc[4][8];
    #pragma unroll
    for (int i = 0; i < 4; ++i)
        #pragma unroll
        for (int j = 0; j < 8; ++j) acc[i][j] = 0.f;

    for (int k0 = 0; k0 < D_MODEL; k0 += 16) {
        float4 av = *(const float4*)&A[(size_t)arow * lda + k0 + akq * 4];
        As[akq*4+0][arow] = av.x;
        As[akq*4+1][arow] = av.y;
        As[akq*4+2][arow] = av.z;
        As[akq*4+3][arow] = av.w;
        #pragma unroll
        for (int p = 0; p < 2; ++p) {
            int k = bk + p * 8;
            *(float4*)&Bs[k][bn4 * 4] =
                *(const float4*)&B[(size_t)(k0 + k) * ldb + bn4 * 4];
        }
        __syncthreads();
        #pragma unroll
        for (int kk = 0; kk < 16; ++kk) {
            float4 a  = *(const float4*)&As[kk][ty * 4];
            float4 b0 = *(const float4*)&Bs[kk][tx * 8];
            float4 b1 = *(const float4*)&Bs[kk][tx * 8 + 4];
            float avv[4] = {a.x, a.y, a.z, a.w};
            float bvv[8] = {b0.x, b0.y, b0.z, b0.w, b1.x, b1.y, b1.z, b1.w};
            #pragma unroll
            for (int i = 0; i < 4; ++i)
                #pragma unroll
                for (int j = 0; j < 8; ++j)
                    acc[i][j] = fmaf(avv[i], bvv[j], acc[i][j]);
        }
        __syncthreads();
    }
    #pragma unroll
    for (int i = 0; i < 4; ++i) {
        #pragma unroll
        for (int j = 0; j < 8; ++j) {
            C[(size_t)(ty * 4 + i) * ldc + tx * 8 + j] =
                acc[i][j] + bias[tx * 8 + j];
        }
    }
}

__global__ __launch_bounds__(256) void proj_kernel(
    const float* __restrict__ x,
    const float* __restrict__ Wq_eff, const float* __restrict__ Wk_eff,
    const float* __restrict__ Wv,
    const float* __restrict__ bq_eff, const float* __restrict__ bk_eff,
    const float* __restrict__ bv,
    float* __restrict__ Y)
{
    int n0 = blockIdx.x * 128;
    int m0 = blockIdx.y * 64;
    const float* B; const float* bias; int ldb;
    if (n0 < 512)       { B = Wq_eff + n0;          bias = bq_eff + n0;          ldb = 512;  }
    else if (n0 < 1024) { B = Wk_eff + (n0 - 512);  bias = bk_eff + (n0 - 512);  ldb = 512;  }
    else                { B = Wv + (n0 - 1024);     bias = bv + (n0 - 1024);     ldb = 1024; }
    gemm_tile_64x128(x + (size_t)m0 * D_MODEL, D_MODEL, B, ldb, bias,
                     Y + (size_t)m0 * NCAT + n0, NCAT);
}

__global__ __launch_bounds__(256) void out_kernel(
    const float* __restrict__ O, const float* __restrict__ Wo,
    const float* __restrict__ bo, float* __restrict__ out)
{
    int n0 = blockIdx.x * 128;
    int m0 = blockIdx.y * 64;
    gemm_tile_64x128(O + (size_t)m0 * D_MODEL, D_MODEL, Wo + n0, D_MODEL,
                     bo + n0, out + (size_t)m0 * D_MODEL + n0, D_MODEL);
}

// ---------------------------------------------------------------------------
// Flash attention, v6 = v5 structure + (256,2) register budget.
// Round-7 lesson (twice-confirmed, r4 & r7): min_waves >= 4 in
// __launch_bounds__ makes the allocator overshoot to the 64-VGPR tier and
// spill o[64] (458 MB scratch writes). (256,2) allocates ~112 VGPR, no
// spill (r6). Uniform blocks from v5 are kept: block = (bh, pq, half)
// does 32 q-rows for BOTH qt=pq and qt=31-pq => exactly 33 KV iters each,
// 1024 identical blocks, 4 blocks/CU sustained (no drain).
// ---------------------------------------------------------------------------
#define SK_LD 36
#define SV_LD 68
#define MASKVAL (-1e30f)

__global__ __launch_bounds__(256, 2) void flash_kernel(
    const float* __restrict__ Y,   // (4096, 2048): q_lr | k_lr | v
    float* __restrict__ O)         // (4096, 1024): (B,T,H,Dh)
{
    const float scale = 0.1767766952966369f;  // 1/sqrt(32)
    const int bh  = blockIdx.x;
    const int pq  = blockIdx.y;                // 0..15
    const int hlf = blockIdx.z;                // 0..1: which 32-row half
    const int b = bh >> 4, h = bh & 15;
    const int tid = threadIdx.x;
    const int row = tid & 31;                  // 0..31
    const int oct = tid >> 5;                  // 0..7, owns 8 kv cols

    __shared__ float smem[64 * SK_LD + 64 * SV_LD];  // sk | sv; reused as accum
    __shared__ float sml[2][8][32];                  // m, l per (oct,row)
    float* sk = smem;                 // [64][SK_LD]
    float* sv = smem + 64 * SK_LD;    // [64][SV_LD]
    float* accum = smem;              // [32][65] after main loop

    #pragma unroll 1
    for (int pass = 0; pass < 2; ++pass) {
        const int qt = pass ? (31 - pq) : pq;
        const int t = qt * 64 + hlf * 32 + row;

        // load q_lr row into registers
        float q[32];
        {
            const float* qrow = Y + (size_t)(b * SEQ + t) * NCAT + h * 32;
            #pragma unroll
            for (int r4 = 0; r4 < 8; ++r4) {
                float4 f = ((const float4*)qrow)[r4];
                q[r4*4+0] = f.x; q[r4*4+1] = f.y; q[r4*4+2] = f.z; q[r4*4+3] = f.w;
            }
        }
        float o[64];
        #pragma unroll
        for (int d = 0; d < 64; ++d) o[d] = 0.f;
        float mrun = MASKVAL, lrun = 0.f;

        for (int jt = 0; jt <= qt; ++jt) {
            // cooperative tile load: 256 threads, 64 kv rows, 4 loaders/row
            {
                const int r  = tid >> 2;
                const int sg = tid & 3;
                const size_t rb = (size_t)(b * SEQ + jt * 64 + r) * NCAT;
                const float* krow = Y + rb + 512 + h * 32;
                const float* vrow = Y + rb + 1024 + h * 64;
                *(float4*)&sk[r * SK_LD + sg * 8]     = ((const float4*)krow)[sg*2];
                *(float4*)&sk[r * SK_LD + sg * 8 + 4] = ((const float4*)krow)[sg*2+1];
                #pragma unroll
                for (int p = 0; p < 4; ++p)
                    *(float4*)&sv[r * SV_LD + sg * 16 + p * 4] =
                        ((const float4*)vrow)[sg * 4 + p];
            }
            __syncthreads();

            // scores for this oct's 8 kv columns (float4 broadcast reads)
            float s[8];
            float mt = MASKVAL;
            #pragma unroll
            for (int jj = 0; jj < 8; ++jj) {
                const int j = oct * 8 + jj;
                const float4* kr = (const float4*)&sk[j * SK_LD];
                float acc = 0.f;
                #pragma unroll
                for (int r4 = 0; r4 < 8; ++r4) {
                    float4 kv = kr[r4];
                    acc = fmaf(q[r4*4+0], kv.x, acc);
                    acc = fmaf(q[r4*4+1], kv.y, acc);
                    acc = fmaf(q[r4*4+2], kv.z, acc);
                    acc = fmaf(q[r4*4+3], kv.w, acc);
                }
                acc *= scale;
                const int gj = jt * 64 + j;
                acc = (gj <= t) ? acc : MASKVAL;
                s[jj] = acc;
                mt = fmaxf(mt, acc);
            }
            const float mnew = fmaxf(mrun, mt);
            const float alpha = expf(mrun - mnew);
            float psum = 0.f;
            #pragma unroll
            for (int jj = 0; jj < 8; ++jj) {
                float p = expf(s[jj] - mnew);
                s[jj] = p;
                psum += p;
            }
            lrun = lrun * alpha + psum;
            #pragma unroll
            for (int d = 0; d < 64; ++d) o[d] *= alpha;
            #pragma unroll
            for (int jj = 0; jj < 8; ++jj) {
                const int j = oct * 8 + jj;
                const float p = s[jj];
                const float4* vr = (const float4*)&sv[j * SV_LD];
                #pragma unroll
                for (int d4 = 0; d4 < 16; ++d4) {
                    float4 vv = vr[d4];
                    o[d4*4+0] = fmaf(p, vv.x, o[d4*4+0]);
                    o[d4*4+1] = fmaf(p, vv.y, o[d4*4+1]);
                    o[d4*4+2] = fmaf(p, vv.z, o[d4*4+2]);
                    o[d4*4+3] = fmaf(p, vv.w, o[d4*4+3]);
                }
            }
            mrun = mnew;
            __syncthreads();
        }

        // combine the 8 oct-partials of each row
        sml[0][oct][row] = mrun;
        sml[1][oct][row] = lrun;
        __syncthreads();
        float mg = MASKVAL;
        #pragma unroll
        for (int qq = 0; qq < 8; ++qq) mg = fmaxf(mg, sml[0][qq][row]);
        float lg = 0.f;
        #pragma unroll
        for (int qq = 0; qq < 8; ++qq)
            lg += sml[1][qq][row] * expf(sml[0][qq][row] - mg);
        const float alpha = expf(mrun - mg);   // 0 for never-valid octs

        // serialized combine: literal o[] indices only (rule #20); the
        // `oct == st` predicate leaves o[] fully register-allocated.
        #pragma unroll
        for (int st = 0; st < 8; ++st) {
            if (oct == st) {
                if (st == 0) {
                    #pragma unroll
                    for (int dd = 0; dd < 64; ++dd)
                        accum[row * 65 + dd] = alpha * o[dd];
                } else {
                    #pragma unroll
                    for (int dd = 0; dd < 64; ++dd)
                        accum[row * 65 + dd] += alpha * o[dd];
                }
            }
            __syncthreads();
        }

        // write output: thread (row, oct) writes 8 contiguous floats
        {
            const float inv = 1.f / lg;
            float* orow = O + (size_t)(b * SEQ + t) * D_MODEL + h * D_HEAD;
            #pragma unroll
            for (int dd = 0; dd < 8; ++dd)
                orow[oct * 8 + dd] =
                    accum[row * 65 + oct * 8 + dd] * inv;
        }
        __syncthreads();   // smem (accum) reused as sk/sv by next pass
    }
}

// ---------------------------------------------------------------------------
extern "C" void kernel_launch(void* const* d_in, const int* in_sizes, int n_in,
                              void* d_out, int out_size, void* d_ws, size_t ws_size,
                              hipStream_t stream)
{
    const float* x      = (const float*)d_in[0];
    const float* Wq     = (const float*)d_in[1];
    const float* bq     = (const float*)d_in[2];
    const float* Wk     = (const float*)d_in[3];
    const float* bk     = (const float*)d_in[4];
    const float* Wv     = (const float*)d_in[5];
    const float* bv     = (const float*)d_in[6];
    const float* Wo     = (const float*)d_in[7];
    const float* bo     = (const float*)d_in[8];
    const float* Wq_lsr = (const float*)d_in[9];
    const float* Wk_lsr = (const float*)d_in[10];
    float* out = (float*)d_out;

    float* ws      = (float*)d_ws;
    float* Wq_eff  = ws;                               // 1024*512
    float* Wk_eff  = Wq_eff + 1024 * 512;              // 1024*512
    float* bq_eff  = Wk_eff + 1024 * 512;              // 512
    float* bk_eff  = bq_eff + 512;                     // 512
    float* Ycat    = bk_eff + 512;                     // 4096*2048
    float* Oacc    = Ycat + (size_t)M_TOT * NCAT;      // 4096*1024

    eff_weight_kernel<<<2048, 256, 0, stream>>>(Wq, Wq_lsr, Wq_eff);
    eff_weight_kernel<<<2048, 256, 0, stream>>>(Wk, Wk_lsr, Wk_eff);
    eff_bias_kernel<<<1, 512, 0, stream>>>(bq, Wq_lsr, bq_eff);
    eff_bias_kernel<<<1, 512, 0, stream>>>(bk, Wk_lsr, bk_eff);

    proj_kernel<<<dim3(NCAT / 128, M_TOT / 64), 256, 0, stream>>>(
        x, Wq_eff, Wk_eff, Wv, bq_eff, bk_eff, bv, Ycat);

    flash_kernel<<<dim3(BATCH * N_HEADS, 16, 2), 256, 0, stream>>>(Ycat, Oacc);

    out_kernel<<<dim3(D_MODEL / 128, M_TOT / 64), 256, 0, stream>>>(
        Oacc, Wo, bo, out);
}

// Round 9
// 425.407 us; speedup vs baseline: 1.7738x; 1.5910x over previous
//
#include <hip/hip_runtime.h>
#include <math.h>

#define D_MODEL 1024
#define N_HEADS 16
#define D_HEAD  64
#define LSR_RANK 32
#define BATCH 2
#define SEQ 2048
#define M_TOT (BATCH*SEQ)          // 4096 rows (B*T)
#define NCAT  2048                 // q_lr(512) | k_lr(512) | v(1024)

typedef __attribute__((ext_vector_type(8))) short short8v;
typedef __attribute__((ext_vector_type(4))) float f32x4;

// bf16 split helpers (truncation: hi rel err 2^-8, hi+lo combined ~2^-16)
static __device__ __forceinline__ ushort bfhi(float f) {
    union { float f; unsigned u; } c; c.f = f;
    return (ushort)(c.u >> 16);
}
static __device__ __forceinline__ float bff(ushort h) {
    union { unsigned u; float f; } c; c.u = ((unsigned)h) << 16;
    return c.f;
}
// split 8 floats (two float4) into hi/lo bf16 short8v's (all literal indices)
static __device__ __forceinline__ void split8(const float4 a, const float4 b,
                                              short8v& h, short8v& l) {
    ushort h0 = bfhi(a.x), h1 = bfhi(a.y), h2 = bfhi(a.z), h3 = bfhi(a.w);
    ushort h4 = bfhi(b.x), h5 = bfhi(b.y), h6 = bfhi(b.z), h7 = bfhi(b.w);
    h[0] = (short)h0; h[1] = (short)h1; h[2] = (short)h2; h[3] = (short)h3;
    h[4] = (short)h4; h[5] = (short)h5; h[6] = (short)h6; h[7] = (short)h7;
    l[0] = (short)bfhi(a.x - bff(h0)); l[1] = (short)bfhi(a.y - bff(h1));
    l[2] = (short)bfhi(a.z - bff(h2)); l[3] = (short)bfhi(a.w - bff(h3));
    l[4] = (short)bfhi(b.x - bff(h4)); l[5] = (short)bfhi(b.y - bff(h5));
    l[6] = (short)bfhi(b.z - bff(h6)); l[7] = (short)bfhi(b.w - bff(h7));
}

// ---------------------------------------------------------------------------
// Weff_tmp[k][base + c] = sum_d W[k, h*64+d] * Wlsr[h, d, r],  c = h*32+r
// (fp32; transposed later into Wcat_t)
// ---------------------------------------------------------------------------
__global__ __launch_bounds__(256) void eff_weight_kernel(
    const float* __restrict__ W, const float* __restrict__ Wlsr,
    float* __restrict__ Weff_tmp, int base)
{
    int idx = blockIdx.x * 256 + threadIdx.x;     // 1024*512 outputs
    int k = idx >> 9;
    int c = idx & 511;
    int h = c >> 5;
    int r = c & 31;
    const float* wrow = W + (size_t)k * D_MODEL + h * D_HEAD;
    const float* lsr  = Wlsr + (size_t)h * D_HEAD * LSR_RANK + r;
    float acc = 0.f;
    #pragma unroll
    for (int d = 0; d < D_HEAD; ++d)
        acc = fmaf(wrow[d], lsr[d * LSR_RANK], acc);
    Weff_tmp[(size_t)k * 1024 + base + c] = acc;
}

// bcat = [bq_eff(512) | bk_eff(512) | bv(1024)]
__global__ __launch_bounds__(256) void eff_bias_kernel(
    const float* __restrict__ bq, const float* __restrict__ Wq_lsr,
    const float* __restrict__ bk, const float* __restrict__ Wk_lsr,
    const float* __restrict__ bv, float* __restrict__ bcat)
{
    int c = blockIdx.x * 256 + threadIdx.x;   // 0..2047
    if (c < 1024) {
        const float* bias = (c < 512) ? bq : bk;
        const float* lsr  = (c < 512) ? Wq_lsr : Wk_lsr;
        int cc = c & 511;
        int h = cc >> 5, r = cc & 31;
        float acc = 0.f;
        #pragma unroll
        for (int d = 0; d < D_HEAD; ++d)
            acc = fmaf(bias[h * D_HEAD + d],
                       lsr[(size_t)h * D_HEAD * LSR_RANK + d * LSR_RANK + r], acc);
        bcat[c] = acc;
    } else {
        bcat[c] = bv[c - 1024];
    }
}

// ---------------------------------------------------------------------------
// 1024x1024 fp32 transpose, 64x64 LDS tiles, coalesced both sides.
// ---------------------------------------------------------------------------
__global__ __launch_bounds__(256) void transpose1024(
    const float* __restrict__ in, float* __restrict__ out)
{
    __shared__ float t[64][65];
    const int tid = threadIdx.x;
    const int r0 = blockIdx.y * 64, c0 = blockIdx.x * 64;
    const int tr = tid >> 4, tc = tid & 15;
    #pragma unroll
    for (int i = 0; i < 4; ++i) {
        float4 v = *(const float4*)&in[(size_t)(r0 + tr + i * 16) * 1024 + c0 + tc * 4];
        t[tr + i * 16][tc * 4 + 0] = v.x;
        t[tr + i * 16][tc * 4 + 1] = v.y;
        t[tr + i * 16][tc * 4 + 2] = v.z;
        t[tr + i * 16][tc * 4 + 3] = v.w;
    }
    __syncthreads();
    #pragma unroll
    for (int i = 0; i < 4; ++i) {
        float4 v;
        v.x = t[tc * 4 + 0][tr + i * 16];
        v.y = t[tc * 4 + 1][tr + i * 16];
        v.z = t[tc * 4 + 2][tr + i * 16];
        v.w = t[tc * 4 + 3][tr + i * 16];
        *(float4*)&out[(size_t)(c0 + tr + i * 16) * 1024 + r0 + tc * 4] = v;
    }
}

// ---------------------------------------------------------------------------
// Split-bf16 MFMA GEMM: C[M][ldc] = A[M][1024] @ Bt[N][1024]^T + bias.
// x*w ~= xh*wh + xh*wl + xl*wh  (rel err ~2^-16, fp32-grade).
// Tile 128x128, BK=32, 256 thr = 4 waves (2x2 quadrants of 64x64),
// each wave 4x4 frags of mfma_f32_16x16x32_bf16. On-the-fly fp32->hi/lo
// split during reg-staged LDS fill; padded LDS stride 40 bf16 (16B-aligned).
// C/D mapping (m89-verified): row = (lane>>4)*4+reg (1st operand),
// col = lane&15 (2nd operand).
// ---------------------------------------------------------------------------
__global__ __launch_bounds__(256) void gemm_bt_split(
    const float* __restrict__ A,    // [M][1024] fp32
    const float* __restrict__ Bt,   // [N][1024] fp32 (B transposed)
    const float* __restrict__ bias, // [N]
    float* __restrict__ C, int ldc)
{
    __shared__ short Ah[128 * 40], Al[128 * 40];
    __shared__ short Bh[128 * 40], Bl[128 * 40];

    const int tid = threadIdx.x;
    const int m0 = blockIdx.y * 128, n0 = blockIdx.x * 128;
    const int wid = tid >> 6, wr = wid >> 1, wc = wid & 1;
    const int lane = tid & 63, fr = lane & 15, fq = lane >> 4;
    const int srow = tid >> 1;            // staging row 0..127
    const int skq  = (tid & 1) << 4;      // staging k-offset 0/16

    f32x4 acc[4][4];
    #pragma unroll
    for (int i = 0; i < 4; ++i)
        #pragma unroll
        for (int j = 0; j < 4; ++j)
            acc[i][j] = (f32x4){0.f, 0.f, 0.f, 0.f};

    const float* Ag = A + (size_t)(m0 + srow) * 1024 + skq;
    const float* Bg = Bt + (size_t)(n0 + srow) * 1024 + skq;
    short* pAh = &Ah[srow * 40 + skq];
    short* pAl = &Al[srow * 40 + skq];
    short* pBh = &Bh[srow * 40 + skq];
    short* pBl = &Bl[srow * 40 + skq];

    for (int k0 = 0; k0 < 1024; k0 += 32) {
        // stage A(128x32) and B(128x32) fp32 -> hi/lo bf16
        float4 a0 = *(const float4*)(Ag + k0);
        float4 a1 = *(const float4*)(Ag + k0 + 4);
        float4 a2 = *(const float4*)(Ag + k0 + 8);
        float4 a3 = *(const float4*)(Ag + k0 + 12);
        float4 b0 = *(const float4*)(Bg + k0);
        float4 b1 = *(const float4*)(Bg + k0 + 4);
        float4 b2 = *(const float4*)(Bg + k0 + 8);
        float4 b3 = *(const float4*)(Bg + k0 + 12);
        short8v h, l;
        split8(a0, a1, h, l);
        *(short8v*)pAh = h;  *(short8v*)pAl = l;
        split8(a2, a3, h, l);
        *(short8v*)(pAh + 8) = h;  *(short8v*)(pAl + 8) = l;
        split8(b0, b1, h, l);
        *(short8v*)pBh = h;  *(short8v*)pBl = l;
        split8(b2, b3, h, l);
        *(short8v*)(pBh + 8) = h;  *(short8v*)(pBl + 8) = l;
        __syncthreads();

        // load fragments: lane fr = 16-dim index, fq = k-group (8 bf16)
        short8v afh[4], afl[4], bfh[4], bfl[4];
        #pragma unroll
        for (int fi = 0; fi < 4; ++fi) {
            const int ar = wr * 64 + fi * 16 + fr;
            afh[fi] = *(const short8v*)&Ah[ar * 40 + fq * 8];
            afl[fi] = *(const short8v*)&Al[ar * 40 + fq * 8];
        }
        #pragma unroll
        for (int bj = 0; bj < 4; ++bj) {
            const int br = wc * 64 + bj * 16 + fr;
            bfh[bj] = *(const short8v*)&Bh[br * 40 + fq * 8];
            bfl[bj] = *(const short8v*)&Bl[br * 40 + fq * 8];
        }
        #pragma unroll
        for (int fi = 0; fi < 4; ++fi) {
            #pragma unroll
            for (int bj = 0; bj < 4; ++bj) {
                acc[fi][bj] = __builtin_amdgcn_mfma_f32_16x16x32_bf16(
                    afh[fi], bfh[bj], acc[fi][bj], 0, 0, 0);
                acc[fi][bj] = __builtin_amdgcn_mfma_f32_16x16x32_bf16(
                    afh[fi], bfl[bj], acc[fi][bj], 0, 0, 0);
                acc[fi][bj] = __builtin_amdgcn_mfma_f32_16x16x32_bf16(
                    afl[fi], bfh[bj], acc[fi][bj], 0, 0, 0);
            }
        }
        __syncthreads();
    }

    // epilogue: C[row][col] = acc + bias[col]
    #pragma unroll
    for (int fi = 0; fi < 4; ++fi) {
        #pragma unroll
        for (int bj = 0; bj < 4; ++bj) {
            const int r = m0 + wr * 64 + fi * 16 + fq * 4;
            const int c = n0 + wc * 64 + bj * 16 + fr;
            const float bv_ = bias[c];
            #pragma unroll
            for (int j = 0; j < 4; ++j)
                C[(size_t)(r + j) * ldc + c] = acc[fi][bj][j] + bv_;
        }
    }
}

// ---------------------------------------------------------------------------
// Flash attention (r6-measured-best variant, verbatim): 256 thr, (256,2),
// grid (32, 32), qt = 31 - blockIdx.y (LPT), literal-index o[] epilogue.
// ---------------------------------------------------------------------------
#define SK_LD 36
#define SV_LD 68
#define MASKVAL (-1e30f)

__global__ __launch_bounds__(256, 2) void flash_kernel(
    const float* __restrict__ Y,   // (4096, 2048): q_lr | k_lr | v
    float* __restrict__ O)         // (4096, 1024): (B,T,H,Dh)
{
    const float scale = 0.1767766952966369f;  // 1/sqrt(32)
    const int bh = blockIdx.x;
    const int qt = 31 - blockIdx.y;            // big tiles first (LPT)
    const int b = bh >> 4, h = bh & 15;
    const int tid = threadIdx.x;
    const int row = tid & 63;
    const int quarter = tid >> 6;              // 0..3 == wave id

    __shared__ float smem[64 * SK_LD + 64 * SV_LD];  // sk | sv; reused as accum
    __shared__ float sml[2][4][64];                  // m, l per (quarter,row)
    float* sk = smem;                 // [64][SK_LD]
    float* sv = smem + 64 * SK_LD;    // [64][SV_LD]
    float* accum = smem;              // [64][65] after main loop

    const int t = qt * 64 + row;

    float q[32];
    {
        const float* qrow = Y + (size_t)(b * SEQ + t) * NCAT + h * 32;
        #pragma unroll
        for (int r4 = 0; r4 < 8; ++r4) {
            float4 f = ((const float4*)qrow)[r4];
            q[r4*4+0] = f.x; q[r4*4+1] = f.y; q[r4*4+2] = f.z; q[r4*4+3] = f.w;
        }
    }
    float o[64];
    #pragma unroll
    for (int d = 0; d < 64; ++d) o[d] = 0.f;
    float mrun = MASKVAL, lrun = 0.f;

    for (int jt = 0; jt <= qt; ++jt) {
        {
            const int r  = tid >> 2;
            const int sg = tid & 3;
            const size_t rb = (size_t)(b * SEQ + jt * 64 + r) * NCAT;
            const float* krow = Y + rb + 512 + h * 32;
            const float* vrow = Y + rb + 1024 + h * 64;
            *(float4*)&sk[r * SK_LD + sg * 8]     = ((const float4*)krow)[sg*2];
            *(float4*)&sk[r * SK_LD + sg * 8 + 4] = ((const float4*)krow)[sg*2+1];
            #pragma unroll
            for (int p = 0; p < 4; ++p)
                *(float4*)&sv[r * SV_LD + sg * 16 + p * 4] =
                    ((const float4*)vrow)[sg * 4 + p];
        }
        __syncthreads();

        float s[16];
        float mt = MASKVAL;
        #pragma unroll
        for (int jj = 0; jj < 16; ++jj) {
            const int j = quarter * 16 + jj;
            const float4* kr = (const float4*)&sk[j * SK_LD];
            float acc = 0.f;
            #pragma unroll
            for (int r4 = 0; r4 < 8; ++r4) {
                float4 kv = kr[r4];
                acc = fmaf(q[r4*4+0], kv.x, acc);
                acc = fmaf(q[r4*4+1], kv.y, acc);
                acc = fmaf(q[r4*4+2], kv.z, acc);
                acc = fmaf(q[r4*4+3], kv.w, acc);
            }
            acc *= scale;
            const int gj = jt * 64 + j;
            acc = (gj <= t) ? acc : MASKVAL;
            s[jj] = acc;
            mt = fmaxf(mt, acc);
        }
        const float mnew = fmaxf(mrun, mt);
        const float alpha = expf(mrun - mnew);
        float psum = 0.f;
        #pragma unroll
        for (int jj = 0; jj < 16; ++jj) {
            float p = expf(s[jj] - mnew);
            s[jj] = p;
            psum += p;
        }
        lrun = lrun * alpha + psum;
        #pragma unroll
        for (int d = 0; d < 64; ++d) o[d] *= alpha;
        #pragma unroll
        for (int jj = 0; jj < 16; ++jj) {
            const int j = quarter * 16 + jj;
            const float p = s[jj];
            const float4* vr = (const float4*)&sv[j * SV_LD];
            #pragma unroll
            for (int d4 = 0; d4 < 16; ++d4) {
                float4 vv = vr[d4];
                o[d4*4+0] = fmaf(p, vv.x, o[d4*4+0]);
                o[d4*4+1] = fmaf(p, vv.y, o[d4*4+1]);
                o[d4*4+2] = fmaf(p, vv.z, o[d4*4+2]);
                o[d4*4+3] = fmaf(p, vv.w, o[d4*4+3]);
            }
        }
        mrun = mnew;
        __syncthreads();
    }

    sml[0][quarter][row] = mrun;
    sml[1][quarter][row] = lrun;
    __syncthreads();
    float mg = MASKVAL;
    #pragma unroll
    for (int qq = 0; qq < 4; ++qq) mg = fmaxf(mg, sml[0][qq][row]);
    float lg = 0.f;
    #pragma unroll
    for (int qq = 0; qq < 4; ++qq)
        lg += sml[1][qq][row] * expf(sml[0][qq][row] - mg);
    const float alpha = expf(mrun - mg);

    #pragma unroll
    for (int st = 0; st < 4; ++st) {
        if (quarter == st) {
            if (st == 0) {
                #pragma unroll
                for (int dd = 0; dd < 64; ++dd)
                    accum[row * 65 + dd] = alpha * o[dd];
            } else {
                #pragma unroll
                for (int dd = 0; dd < 64; ++dd)
                    accum[row * 65 + dd] += alpha * o[dd];
            }
        }
        __syncthreads();
    }

    {
        const float inv = 1.f / lg;
        float* orow = O + (size_t)(b * SEQ + t) * D_MODEL + h * D_HEAD;
        #pragma unroll
        for (int dd = 0; dd < 16; ++dd)
            orow[quarter * 16 + dd] =
                accum[row * 65 + quarter * 16 + dd] * inv;
    }
}

// ---------------------------------------------------------------------------
extern "C" void kernel_launch(void* const* d_in, const int* in_sizes, int n_in,
                              void* d_out, int out_size, void* d_ws, size_t ws_size,
                              hipStream_t stream)
{
    const float* x      = (const float*)d_in[0];
    const float* Wq     = (const float*)d_in[1];
    const float* bq     = (const float*)d_in[2];
    const float* Wk     = (const float*)d_in[3];
    const float* bk     = (const float*)d_in[4];
    const float* Wv     = (const float*)d_in[5];
    const float* bv     = (const float*)d_in[6];
    const float* Wo     = (const float*)d_in[7];
    const float* bo     = (const float*)d_in[8];
    const float* Wq_lsr = (const float*)d_in[9];
    const float* Wk_lsr = (const float*)d_in[10];
    float* out = (float*)d_out;

    // workspace (floats), ~56 MB total with aliasing:
    float* ws       = (float*)d_ws;
    float* Wcat_t   = ws;                                  // 2048*1024
    float* bcat     = Wcat_t + (size_t)2048 * 1024;        // 2048
    float* Ycat     = bcat + 2048;                         // 4096*2048
    float* Oacc     = Ycat + (size_t)M_TOT * NCAT;         // 4096*1024
    float* Weff_tmp = Oacc;           // alias: dead before flash writes Oacc
    float* Wo_t     = Ycat;           // alias: Ycat dead after flash

    eff_weight_kernel<<<2048, 256, 0, stream>>>(Wq, Wq_lsr, Weff_tmp, 0);
    eff_weight_kernel<<<2048, 256, 0, stream>>>(Wk, Wk_lsr, Weff_tmp, 512);
    eff_bias_kernel<<<8, 256, 0, stream>>>(bq, Wq_lsr, bk, Wk_lsr, bv, bcat);

    transpose1024<<<dim3(16, 16), 256, 0, stream>>>(Weff_tmp, Wcat_t);
    transpose1024<<<dim3(16, 16), 256, 0, stream>>>(Wv, Wcat_t + (size_t)1024 * 1024);

    // Ycat = x @ [Wq_eff|Wk_eff|Wv] + bcat   (split-bf16 MFMA)
    gemm_bt_split<<<dim3(16, 32), 256, 0, stream>>>(x, Wcat_t, bcat, Ycat, NCAT);

    flash_kernel<<<dim3(BATCH * N_HEADS, 32), 256, 0, stream>>>(Ycat, Oacc);

    transpose1024<<<dim3(16, 16), 256, 0, stream>>>(Wo, Wo_t);

    // out = Oacc @ Wo + bo   (split-bf16 MFMA)
    gemm_bt_split<<<dim3(8, 32), 256, 0, stream>>>(Oacc, Wo_t, bo, out, D_MODEL);
}

// Round 10
// 327.724 us; speedup vs baseline: 2.3024x; 1.2981x over previous
//
#include <hip/hip_runtime.h>
#include <math.h>

#define D_MODEL 1024
#define N_HEADS 16
#define D_HEAD  64
#define LSR_RANK 32
#define BATCH 2
#define SEQ 2048
#define M_TOT (BATCH*SEQ)

typedef __attribute__((ext_vector_type(8))) short short8v;
typedef __attribute__((ext_vector_type(4))) float f32x4;

static __device__ __forceinline__ ushort bfhi(float f) {
    union { float f; unsigned u; } c; c.f = f;
    return (ushort)(c.u >> 16);
}
static __device__ __forceinline__ float bff(ushort h) {
    union { unsigned u; float f; } c; c.u = ((unsigned)h) << 16;
    return c.f;
}
static __device__ __forceinline__ ushort f2bf_rn(float f) {  // round-nearest
    union { float f; unsigned u; } c; c.f = f;
    unsigned r = c.u + 0x7FFF + ((c.u >> 16) & 1);
    return (ushort)(r >> 16);
}
static __device__ __forceinline__ void split8(const float4 a, const float4 b,
                                              short8v& h, short8v& l) {
    ushort h0 = bfhi(a.x), h1 = bfhi(a.y), h2 = bfhi(a.z), h3 = bfhi(a.w);
    ushort h4 = bfhi(b.x), h5 = bfhi(b.y), h6 = bfhi(b.z), h7 = bfhi(b.w);
    h[0] = (short)h0; h[1] = (short)h1; h[2] = (short)h2; h[3] = (short)h3;
    h[4] = (short)h4; h[5] = (short)h5; h[6] = (short)h6; h[7] = (short)h7;
    l[0] = (short)bfhi(a.x - bff(h0)); l[1] = (short)bfhi(a.y - bff(h1));
    l[2] = (short)bfhi(a.z - bff(h2)); l[3] = (short)bfhi(a.w - bff(h3));
    l[4] = (short)bfhi(b.x - bff(h4)); l[5] = (short)bfhi(b.y - bff(h5));
    l[6] = (short)bfhi(b.z - bff(h6)); l[7] = (short)bfhi(b.w - bff(h7));
}

// ---------------------------------------------------------------------------
// Weff_tmp[k][base+c] = sum_d W[k, h*64+d] * Wlsr[h, d, r]
// ---------------------------------------------------------------------------
__global__ __launch_bounds__(256) void eff_weight_kernel(
    const float* __restrict__ W, const float* __restrict__ Wlsr,
    float* __restrict__ Weff_tmp, int base)
{
    int idx = blockIdx.x * 256 + threadIdx.x;
    int k = idx >> 9;
    int c = idx & 511;
    int h = c >> 5;
    int r = c & 31;
    const float* wrow = W + (size_t)k * D_MODEL + h * D_HEAD;
    const float* lsr  = Wlsr + (size_t)h * D_HEAD * LSR_RANK + r;
    float acc = 0.f;
    #pragma unroll
    for (int d = 0; d < D_HEAD; ++d)
        acc = fmaf(wrow[d], lsr[d * LSR_RANK], acc);
    Weff_tmp[(size_t)k * 1024 + base + c] = acc;
}

// bcat = [bq_eff(512) | bk_eff(512) | bv(1024)]
__global__ __launch_bounds__(256) void eff_bias_kernel(
    const float* __restrict__ bq, const float* __restrict__ Wq_lsr,
    const float* __restrict__ bk, const float* __restrict__ Wk_lsr,
    const float* __restrict__ bv, float* __restrict__ bcat)
{
    int c = blockIdx.x * 256 + threadIdx.x;
    if (c < 1024) {
        const float* bias = (c < 512) ? bq : bk;
        const float* lsr  = (c < 512) ? Wq_lsr : Wk_lsr;
        int cc = c & 511;
        int h = cc >> 5, r = cc & 31;
        float acc = 0.f;
        #pragma unroll
        for (int d = 0; d < D_HEAD; ++d)
            acc = fmaf(bias[h * D_HEAD + d],
                       lsr[(size_t)h * D_HEAD * LSR_RANK + d * LSR_RANK + r], acc);
        bcat[c] = acc;
    } else {
        bcat[c] = bv[c - 1024];
    }
}

// ---------------------------------------------------------------------------
// 1024x1024 fp32 transpose
// ---------------------------------------------------------------------------
__global__ __launch_bounds__(256) void transpose1024(
    const float* __restrict__ in, float* __restrict__ out)
{
    __shared__ float t[64][65];
    const int tid = threadIdx.x;
    const int r0 = blockIdx.y * 64, c0 = blockIdx.x * 64;
    const int tr = tid >> 4, tc = tid & 15;
    #pragma unroll
    for (int i = 0; i < 4; ++i) {
        float4 v = *(const float4*)&in[(size_t)(r0 + tr + i * 16) * 1024 + c0 + tc * 4];
        t[tr + i * 16][tc * 4 + 0] = v.x;
        t[tr + i * 16][tc * 4 + 1] = v.y;
        t[tr + i * 16][tc * 4 + 2] = v.z;
        t[tr + i * 16][tc * 4 + 3] = v.w;
    }
    __syncthreads();
    #pragma unroll
    for (int i = 0; i < 4; ++i) {
        float4 v;
        v.x = t[tc * 4 + 0][tr + i * 16];
        v.y = t[tc * 4 + 1][tr + i * 16];
        v.z = t[tc * 4 + 2][tr + i * 16];
        v.w = t[tc * 4 + 3][tr + i * 16];
        *(float4*)&out[(size_t)(c0 + tr + i * 16) * 1024 + r0 + tc * 4] = v;
    }
}

// ---------------------------------------------------------------------------
// Split-bf16 MFMA GEMM, 128x128 tile, BK=32. C cols < csplit -> C0, else C1
// (both ldc 1024). Conventions validated in r9 (passed).
// ---------------------------------------------------------------------------
__global__ __launch_bounds__(256) void gemm_bt_split(
    const float* __restrict__ A,
    const float* __restrict__ Bt,
    const float* __restrict__ bias,
    float* __restrict__ C0, float* __restrict__ C1, int csplit)
{
    __shared__ __align__(16) short Ah[128 * 40], Al[128 * 40];
    __shared__ __align__(16) short Bh[128 * 40], Bl[128 * 40];

    const int tid = threadIdx.x;
    const int m0 = blockIdx.y * 128, n0 = blockIdx.x * 128;
    const int wid = tid >> 6, wr = wid >> 1, wc = wid & 1;
    const int lane = tid & 63, fr = lane & 15, fq = lane >> 4;
    const int srow = tid >> 1;
    const int skq  = (tid & 1) << 4;

    float* Cw; int ncol;
    if (n0 < csplit) { Cw = C0; ncol = n0; }
    else             { Cw = C1; ncol = n0 - csplit; }

    f32x4 acc[4][4];
    #pragma unroll
    for (int i = 0; i < 4; ++i)
        #pragma unroll
        for (int j = 0; j < 4; ++j)
            acc[i][j] = (f32x4){0.f, 0.f, 0.f, 0.f};

    const float* Ag = A + (size_t)(m0 + srow) * 1024 + skq;
    const float* Bg = Bt + (size_t)(n0 + srow) * 1024 + skq;
    short* pAh = &Ah[srow * 40 + skq];
    short* pAl = &Al[srow * 40 + skq];
    short* pBh = &Bh[srow * 40 + skq];
    short* pBl = &Bl[srow * 40 + skq];

    for (int k0 = 0; k0 < 1024; k0 += 32) {
        float4 a0 = *(const float4*)(Ag + k0);
        float4 a1 = *(const float4*)(Ag + k0 + 4);
        float4 a2 = *(const float4*)(Ag + k0 + 8);
        float4 a3 = *(const float4*)(Ag + k0 + 12);
        float4 b0 = *(const float4*)(Bg + k0);
        float4 b1 = *(const float4*)(Bg + k0 + 4);
        float4 b2 = *(const float4*)(Bg + k0 + 8);
        float4 b3 = *(const float4*)(Bg + k0 + 12);
        short8v h, l;
        split8(a0, a1, h, l);
        *(short8v*)pAh = h;  *(short8v*)pAl = l;
        split8(a2, a3, h, l);
        *(short8v*)(pAh + 8) = h;  *(short8v*)(pAl + 8) = l;
        split8(b0, b1, h, l);
        *(short8v*)pBh = h;  *(short8v*)pBl = l;
        split8(b2, b3, h, l);
        *(short8v*)(pBh + 8) = h;  *(short8v*)(pBl + 8) = l;
        __syncthreads();

        short8v afh[4], afl[4], bfh[4], bfl[4];
        #pragma unroll
        for (int fi = 0; fi < 4; ++fi) {
            const int ar = wr * 64 + fi * 16 + fr;
            afh[fi] = *(const short8v*)&Ah[ar * 40 + fq * 8];
            afl[fi] = *(const short8v*)&Al[ar * 40 + fq * 8];
        }
        #pragma unroll
        for (int bj = 0; bj < 4; ++bj) {
            const int br = wc * 64 + bj * 16 + fr;
            bfh[bj] = *(const short8v*)&Bh[br * 40 + fq * 8];
            bfl[bj] = *(const short8v*)&Bl[br * 40 + fq * 8];
        }
        #pragma unroll
        for (int fi = 0; fi < 4; ++fi) {
            #pragma unroll
            for (int bj = 0; bj < 4; ++bj) {
                acc[fi][bj] = __builtin_amdgcn_mfma_f32_16x16x32_bf16(
                    afh[fi], bfh[bj], acc[fi][bj], 0, 0, 0);
                acc[fi][bj] = __builtin_amdgcn_mfma_f32_16x16x32_bf16(
                    afh[fi], bfl[bj], acc[fi][bj], 0, 0, 0);
                acc[fi][bj] = __builtin_amdgcn_mfma_f32_16x16x32_bf16(
                    afl[fi], bfh[bj], acc[fi][bj], 0, 0, 0);
            }
        }
        __syncthreads();
    }

    #pragma unroll
    for (int fi = 0; fi < 4; ++fi) {
        #pragma unroll
        for (int bj = 0; bj < 4; ++bj) {
            const int r = m0 + wr * 64 + fi * 16 + fq * 4;
            const int c = ncol + wc * 64 + bj * 16 + fr;
            const float bv_ = bias[n0 - ncol + c];
            #pragma unroll
            for (int j = 0; j < 4; ++j)
                Cw[(size_t)(r + j) * 1024 + c] = acc[fi][bj][j] + bv_;
        }
    }
}

// ---------------------------------------------------------------------------
// V transpose + bf16 split: Vtmp[4096][1024] -> Vth/Vtl [bh][64 d][2048 t]
// ---------------------------------------------------------------------------
__global__ __launch_bounds__(256) void vt_prep(
    const float* __restrict__ Vtmp,
    short* __restrict__ Vth, short* __restrict__ Vtl)
{
    __shared__ float t[64][68];
    const int bh = blockIdx.x;
    const int b = bh >> 4, h = bh & 15;
    const int t0 = blockIdx.y * 64;
    const int tid = threadIdx.x;
    {
        const int tl = tid >> 2, sg = tid & 3;
        const float* vp = Vtmp + (size_t)(b * SEQ + t0 + tl) * 1024 + h * 64 + sg * 16;
        #pragma unroll
        for (int i = 0; i < 4; ++i)
            *(float4*)&t[tl][sg * 16 + i * 4] = *(const float4*)(vp + i * 4);
    }
    __syncthreads();
    {
        const int d = tid >> 2, sg = tid & 3;
        short8v h0, h1, l0, l1;
        #pragma unroll
        for (int i = 0; i < 8; ++i) {
            float f = t[sg * 16 + i][d];
            ushort hi = bfhi(f);
            h0[i] = (short)hi;
            l0[i] = (short)bfhi(f - bff(hi));
        }
        #pragma unroll
        for (int i = 0; i < 8; ++i) {
            float f = t[sg * 16 + 8 + i][d];
            ushort hi = bfhi(f);
            h1[i] = (short)hi;
            l1[i] = (short)bfhi(f - bff(hi));
        }
        short* oh = Vth + ((size_t)bh * 64 + d) * 2048 + t0 + sg * 16;
        short* ol = Vtl + ((size_t)bh * 64 + d) * 2048 + t0 + sg * 16;
        *(short8v*)oh = h0;       *(short8v*)(oh + 8) = h1;
        *(short8v*)ol = l0;       *(short8v*)(ol + 8) = l1;
    }
}

// ---------------------------------------------------------------------------
// MFMA flash attention. Block 256 = 4 waves; wave w owns q-rows w*16..+16 of
// q-tile qt (full 64 kv cols). QK^T split-bf16 (3 mfma x 4 coltiles), wave-
// parallel softmax via shfl_xor within 16-lane groups, PV via P(bf16 rounded,
// LDS relayout) x Vt(split, global pre-transposed). 2 barriers/tile.
// ---------------------------------------------------------------------------
#define KH_LD 40
#define P_LD  72
#define MASKVAL (-1e30f)

__global__ __launch_bounds__(256, 2) void flash_mfma(
    const float* __restrict__ Yqk,   // [4096][1024]: q_lr(512) | k_lr(512)
    const short* __restrict__ Vth,   // [32][64][2048] bf16 hi
    const short* __restrict__ Vtl,   // lo
    float* __restrict__ O)           // [4096][1024] (B,T,H,Dh)
{
    const float scale = 0.1767766952966369f;  // 1/sqrt(32)
    const int bh = blockIdx.x;
    const int b = bh >> 4, h = bh & 15;
    const int qt = 31 - blockIdx.y;            // LPT
    const int tid = threadIdx.x;
    const int w = tid >> 6;
    const int lane = tid & 63;
    const int fr = lane & 15, fq = lane >> 4;

    __shared__ __align__(16) short Kh[64 * KH_LD], Kl[64 * KH_LD];
    __shared__ __align__(16) short Pl[64 * P_LD];

    // hoisted Q fragment (hi/lo): row = w*16+fr, k = fq*8..+8
    short8v aqh, aql;
    {
        const float* qp = Yqk + (size_t)(b * SEQ + qt * 64 + w * 16 + fr) * 1024
                          + h * 32 + fq * 8;
        split8(*(const float4*)qp, *(const float4*)(qp + 4), aqh, aql);
    }

    f32x4 acc0 = {0,0,0,0}, acc1 = {0,0,0,0}, acc2 = {0,0,0,0}, acc3 = {0,0,0,0};
    float m_[4], l_[4];
    #pragma unroll
    for (int r = 0; r < 4; ++r) { m_[r] = MASKVAL; l_[r] = 0.f; }

    const short* vb_h = Vth + (size_t)bh * 64 * 2048;
    const short* vb_l = Vtl + (size_t)bh * 64 * 2048;

    for (int jt = 0; jt <= qt; ++jt) {
        // stage K tile (64 kv x 32 r) as hi/lo bf16
        {
            const int kv = tid >> 2, quad = tid & 3;
            const float* kp = Yqk + (size_t)(b * SEQ + jt * 64 + kv) * 1024
                              + 512 + h * 32 + quad * 8;
            short8v kh, kl;
            split8(*(const float4*)kp, *(const float4*)(kp + 4), kh, kl);
            *(short8v*)&Kh[kv * KH_LD + quad * 8] = kh;
            *(short8v*)&Kl[kv * KH_LD + quad * 8] = kl;
        }
        __syncthreads();

        // S = Q K^T (split), 4 col-tiles of 16 kv
        f32x4 s0 = {0,0,0,0}, s1 = {0,0,0,0}, s2 = {0,0,0,0}, s3 = {0,0,0,0};
        #define QK_CT(CT, SS) { \
            short8v kbh = *(const short8v*)&Kh[(CT * 16 + fr) * KH_LD + fq * 8]; \
            short8v kbl = *(const short8v*)&Kl[(CT * 16 + fr) * KH_LD + fq * 8]; \
            SS = __builtin_amdgcn_mfma_f32_16x16x32_bf16(aqh, kbh, SS, 0, 0, 0); \
            SS = __builtin_amdgcn_mfma_f32_16x16x32_bf16(aqh, kbl, SS, 0, 0, 0); \
            SS = __builtin_amdgcn_mfma_f32_16x16x32_bf16(aql, kbh, SS, 0, 0, 0); }
        QK_CT(0, s0) QK_CT(1, s1) QK_CT(2, s2) QK_CT(3, s3)
        #undef QK_CT

        s0 *= scale; s1 *= scale; s2 *= scale; s3 *= scale;

        if (jt == qt) {   // diagonal tile: causal mask (kv_local <= q_local)
            #pragma unroll
            for (int r = 0; r < 4; ++r) {
                const int q_l = w * 16 + fq * 4 + r;
                s0[r] = (fr      <= q_l) ? s0[r] : MASKVAL;
                s1[r] = (16 + fr <= q_l) ? s1[r] : MASKVAL;
                s2[r] = (32 + fr <= q_l) ? s2[r] : MASKVAL;
                s3[r] = (48 + fr <= q_l) ? s3[r] : MASKVAL;
            }
        }

        // online softmax per q-row (reg); row spread over 16 lanes (same fq)
        float al[4];
        #pragma unroll
        for (int r = 0; r < 4; ++r) {
            float mt = fmaxf(fmaxf(s0[r], s1[r]), fmaxf(s2[r], s3[r]));
            mt = fmaxf(mt, __shfl_xor(mt, 1));
            mt = fmaxf(mt, __shfl_xor(mt, 2));
            mt = fmaxf(mt, __shfl_xor(mt, 4));
            mt = fmaxf(mt, __shfl_xor(mt, 8));
            const float mnew = fmaxf(m_[r], mt);
            al[r] = __expf(m_[r] - mnew);
            m_[r] = mnew;
            s0[r] = __expf(s0[r] - mnew);
            s1[r] = __expf(s1[r] - mnew);
            s2[r] = __expf(s2[r] - mnew);
            s3[r] = __expf(s3[r] - mnew);
            float ps = s0[r] + s1[r] + s2[r] + s3[r];
            ps += __shfl_xor(ps, 1);
            ps += __shfl_xor(ps, 2);
            ps += __shfl_xor(ps, 4);
            ps += __shfl_xor(ps, 8);
            l_[r] = l_[r] * al[r] + ps;
        }

        // write P (bf16, rounded) into per-wave LDS region in A-frag layout
        #pragma unroll
        for (int r = 0; r < 4; ++r) {
            const int prow = w * 16 + fq * 4 + r;
            Pl[prow * P_LD +      fr] = (short)f2bf_rn(s0[r]);
            Pl[prow * P_LD + 16 + fr] = (short)f2bf_rn(s1[r]);
            Pl[prow * P_LD + 32 + fr] = (short)f2bf_rn(s2[r]);
            Pl[prow * P_LD + 48 + fr] = (short)f2bf_rn(s3[r]);
        }
        // rescale accumulators (row r <- al[r])
        #pragma unroll
        for (int r = 0; r < 4; ++r) {
            acc0[r] *= al[r]; acc1[r] *= al[r];
            acc2[r] *= al[r]; acc3[r] *= al[r];
        }
        __syncthreads();   // P visible (also: all waves past QK reads of Kh)

        // PV: A = P (rows w*16..+16), B = Vt (split)
        short8v pa0 = *(const short8v*)&Pl[(w * 16 + fr) * P_LD + fq * 8];
        short8v pa1 = *(const short8v*)&Pl[(w * 16 + fr) * P_LD + 32 + fq * 8];
        const size_t vcol = (size_t)jt * 64;
        #define PV_DT(DT, AC) { \
            const short* vh = vb_h + ((size_t)(DT * 16 + fr)) * 2048 + vcol; \
            const short* vl = vb_l + ((size_t)(DT * 16 + fr)) * 2048 + vcol; \
            short8v vh0 = *(const short8v*)(vh + fq * 8); \
            short8v vl0 = *(const short8v*)(vl + fq * 8); \
            AC = __builtin_amdgcn_mfma_f32_16x16x32_bf16(pa0, vh0, AC, 0, 0, 0); \
            AC = __builtin_amdgcn_mfma_f32_16x16x32_bf16(pa0, vl0, AC, 0, 0, 0); \
            short8v vh1 = *(const short8v*)(vh + 32 + fq * 8); \
            short8v vl1 = *(const short8v*)(vl + 32 + fq * 8); \
            AC = __builtin_amdgcn_mfma_f32_16x16x32_bf16(pa1, vh1, AC, 0, 0, 0); \
            AC = __builtin_amdgcn_mfma_f32_16x16x32_bf16(pa1, vl1, AC, 0, 0, 0); }
        PV_DT(0, acc0) PV_DT(1, acc1) PV_DT(2, acc2) PV_DT(3, acc3)
        #undef PV_DT
    }

    // epilogue: O[q][d] = acc / l
    #pragma unroll
    for (int r = 0; r < 4; ++r) {
        const float inv = 1.f / l_[r];
        const int trow = qt * 64 + w * 16 + fq * 4 + r;
        float* op = O + (size_t)(b * SEQ + trow) * 1024 + h * 64;
        op[     fr] = acc0[r] * inv;
        op[16 + fr] = acc1[r] * inv;
        op[32 + fr] = acc2[r] * inv;
        op[48 + fr] = acc3[r] * inv;
    }
}

// ---------------------------------------------------------------------------
extern "C" void kernel_launch(void* const* d_in, const int* in_sizes, int n_in,
                              void* d_out, int out_size, void* d_ws, size_t ws_size,
                              hipStream_t stream)
{
    const float* x      = (const float*)d_in[0];
    const float* Wq     = (const float*)d_in[1];
    const float* bq     = (const float*)d_in[2];
    const float* Wk     = (const float*)d_in[3];
    const float* bk     = (const float*)d_in[4];
    const float* Wv     = (const float*)d_in[5];
    const float* bv     = (const float*)d_in[6];
    const float* Wo     = (const float*)d_in[7];
    const float* bo     = (const float*)d_in[8];
    const float* Wq_lsr = (const float*)d_in[9];
    const float* Wk_lsr = (const float*)d_in[10];
    float* out = (float*)d_out;

    // workspace (floats): ~57 MB
    float* ws     = (float*)d_ws;
    float* Wcat_t = ws;                                   // 2M floats
    float* bcat   = Wcat_t + (size_t)2048 * 1024;         // 2048
    float* Yqk    = bcat + 2048;                          // 4M
    float* Vtmp   = Yqk + (size_t)M_TOT * 1024;           // 4M (= Oacc later)
    short* Vth    = (short*)(Vtmp + (size_t)M_TOT * 1024);// 4.2M shorts
    short* Vtl    = Vth + (size_t)32 * 64 * 2048;         // 4.2M shorts
    float* Weff_tmp = (float*)Vth;   // alias: dead before vt_prep writes Vth
    float* Oacc   = Vtmp;            // alias: fp32 V dead after vt_prep
    float* Wo_t   = Wcat_t;          // alias: Wcat_t dead after proj

    eff_weight_kernel<<<2048, 256, 0, stream>>>(Wq, Wq_lsr, Weff_tmp, 0);
    eff_weight_kernel<<<2048, 256, 0, stream>>>(Wk, Wk_lsr, Weff_tmp, 512);
    eff_bias_kernel<<<8, 256, 0, stream>>>(bq, Wq_lsr, bk, Wk_lsr, bv, bcat);

    transpose1024<<<dim3(16, 16), 256, 0, stream>>>(Weff_tmp, Wcat_t);
    transpose1024<<<dim3(16, 16), 256, 0, stream>>>(Wv, Wcat_t + (size_t)1024 * 1024);

    // [Yqk | Vtmp] = x @ [Wq_eff|Wk_eff|Wv] + bcat
    gemm_bt_split<<<dim3(16, 32), 256, 0, stream>>>(
        x, Wcat_t, bcat, Yqk, Vtmp, 1024);

    vt_prep<<<dim3(32, 32), 256, 0, stream>>>(Vtmp, Vth, Vtl);

    transpose1024<<<dim3(16, 16), 256, 0, stream>>>(Wo, Wo_t);

    flash_mfma<<<dim3(32, 32), 256, 0, stream>>>(Yqk, Vth, Vtl, Oacc);

    // out = Oacc @ Wo + bo
    gemm_bt_split<<<dim3(8, 32), 256, 0, stream>>>(
        Oacc, Wo_t, bo, out, out, 1 << 30);
}

// Round 11
// 269.195 us; speedup vs baseline: 2.8031x; 1.2174x over previous
//
#include <hip/hip_runtime.h>
#include <math.h>

#define D_MODEL 1024
#define N_HEADS 16
#define D_HEAD  64
#define LSR_RANK 32
#define BATCH 2
#define SEQ 2048
#define M_TOT (BATCH*SEQ)

typedef __attribute__((ext_vector_type(8))) short short8v;
typedef __attribute__((ext_vector_type(4))) float f32x4;

static __device__ __forceinline__ ushort bfhi(float f) {
    union { float f; unsigned u; } c; c.f = f;
    return (ushort)(c.u >> 16);
}
static __device__ __forceinline__ float bff(ushort h) {
    union { unsigned u; float f; } c; c.u = ((unsigned)h) << 16;
    return c.f;
}
static __device__ __forceinline__ ushort f2bf_rn(float f) {
    union { float f; unsigned u; } c; c.f = f;
    unsigned r = c.u + 0x7FFF + ((c.u >> 16) & 1);
    return (ushort)(r >> 16);
}
static __device__ __forceinline__ void split8(const float4 a, const float4 b,
                                              short8v& h, short8v& l) {
    ushort h0 = bfhi(a.x), h1 = bfhi(a.y), h2 = bfhi(a.z), h3 = bfhi(a.w);
    ushort h4 = bfhi(b.x), h5 = bfhi(b.y), h6 = bfhi(b.z), h7 = bfhi(b.w);
    h[0] = (short)h0; h[1] = (short)h1; h[2] = (short)h2; h[3] = (short)h3;
    h[4] = (short)h4; h[5] = (short)h5; h[6] = (short)h6; h[7] = (short)h7;
    l[0] = (short)bfhi(a.x - bff(h0)); l[1] = (short)bfhi(a.y - bff(h1));
    l[2] = (short)bfhi(a.z - bff(h2)); l[3] = (short)bfhi(a.w - bff(h3));
    l[4] = (short)bfhi(b.x - bff(h4)); l[5] = (short)bfhi(b.y - bff(h5));
    l[6] = (short)bfhi(b.z - bff(h6)); l[7] = (short)bfhi(b.w - bff(h7));
}

// ---------------------------------------------------------------------------
// Weff_tmp[k][base+c] = sum_d W[k, h*64+d] * Wlsr[h, d, r]
// ---------------------------------------------------------------------------
__global__ __launch_bounds__(256) void eff_weight_kernel(
    const float* __restrict__ W, const float* __restrict__ Wlsr,
    float* __restrict__ Weff_tmp, int base)
{
    int idx = blockIdx.x * 256 + threadIdx.x;
    int k = idx >> 9;
    int c = idx & 511;
    int h = c >> 5;
    int r = c & 31;
    const float* wrow = W + (size_t)k * D_MODEL + h * D_HEAD;
    const float* lsr  = Wlsr + (size_t)h * D_HEAD * LSR_RANK + r;
    float acc = 0.f;
    #pragma unroll
    for (int d = 0; d < D_HEAD; ++d)
        acc = fmaf(wrow[d], lsr[d * LSR_RANK], acc);
    Weff_tmp[(size_t)k * 1024 + base + c] = acc;
}

__global__ __launch_bounds__(256) void eff_bias_kernel(
    const float* __restrict__ bq, const float* __restrict__ Wq_lsr,
    const float* __restrict__ bk, const float* __restrict__ Wk_lsr,
    const float* __restrict__ bv, float* __restrict__ bcat)
{
    int c = blockIdx.x * 256 + threadIdx.x;
    if (c < 1024) {
        const float* bias = (c < 512) ? bq : bk;
        const float* lsr  = (c < 512) ? Wq_lsr : Wk_lsr;
        int cc = c & 511;
        int h = cc >> 5, r = cc & 31;
        float acc = 0.f;
        #pragma unroll
        for (int d = 0; d < D_HEAD; ++d)
            acc = fmaf(bias[h * D_HEAD + d],
                       lsr[(size_t)h * D_HEAD * LSR_RANK + d * LSR_RANK + r], acc);
        bcat[c] = acc;
    } else {
        bcat[c] = bv[c - 1024];
    }
}

// ---------------------------------------------------------------------------
// 1024x1024 fp32 transpose
// ---------------------------------------------------------------------------
__global__ __launch_bounds__(256) void transpose1024(
    const float* __restrict__ in, float* __restrict__ out)
{
    __shared__ float t[64][65];
    const int tid = threadIdx.x;
    const int r0 = blockIdx.y * 64, c0 = blockIdx.x * 64;
    const int tr = tid >> 4, tc = tid & 15;
    #pragma unroll
    for (int i = 0; i < 4; ++i) {
        float4 v = *(const float4*)&in[(size_t)(r0 + tr + i * 16) * 1024 + c0 + tc * 4];
        t[tr + i * 16][tc * 4 + 0] = v.x;
        t[tr + i * 16][tc * 4 + 1] = v.y;
        t[tr + i * 16][tc * 4 + 2] = v.z;
        t[tr + i * 16][tc * 4 + 3] = v.w;
    }
    __syncthreads();
    #pragma unroll
    for (int i = 0; i < 4; ++i) {
        float4 v;
        v.x = t[tc * 4 + 0][tr + i * 16];
        v.y = t[tc * 4 + 1][tr + i * 16];
        v.z = t[tc * 4 + 2][tr + i * 16];
        v.w = t[tc * 4 + 3][tr + i * 16];
        *(float4*)&out[(size_t)(c0 + tr + i * 16) * 1024 + r0 + tc * 4] = v;
    }
}

// ---------------------------------------------------------------------------
// Split-bf16 MFMA GEMM (r9/r10-validated), 128x128 tile, BK=32.
// ---------------------------------------------------------------------------
__global__ __launch_bounds__(256) void gemm_bt_split(
    const float* __restrict__ A,
    const float* __restrict__ Bt,
    const float* __restrict__ bias,
    float* __restrict__ C0, float* __restrict__ C1, int csplit)
{
    __shared__ __align__(16) short Ah[128 * 40], Al[128 * 40];
    __shared__ __align__(16) short Bh[128 * 40], Bl[128 * 40];

    const int tid = threadIdx.x;
    const int m0 = blockIdx.y * 128, n0 = blockIdx.x * 128;
    const int wid = tid >> 6, wr = wid >> 1, wc = wid & 1;
    const int lane = tid & 63, fr = lane & 15, fq = lane >> 4;
    const int srow = tid >> 1;
    const int skq  = (tid & 1) << 4;

    float* Cw; int ncol;
    if (n0 < csplit) { Cw = C0; ncol = n0; }
    else             { Cw = C1; ncol = n0 - csplit; }

    f32x4 acc[4][4];
    #pragma unroll
    for (int i = 0; i < 4; ++i)
        #pragma unroll
        for (int j = 0; j < 4; ++j)
            acc[i][j] = (f32x4){0.f, 0.f, 0.f, 0.f};

    const float* Ag = A + (size_t)(m0 + srow) * 1024 + skq;
    const float* Bg = Bt + (size_t)(n0 + srow) * 1024 + skq;
    short* pAh = &Ah[srow * 40 + skq];
    short* pAl = &Al[srow * 40 + skq];
    short* pBh = &Bh[srow * 40 + skq];
    short* pBl = &Bl[srow * 40 + skq];

    for (int k0 = 0; k0 < 1024; k0 += 32) {
        float4 a0 = *(const float4*)(Ag + k0);
        float4 a1 = *(const float4*)(Ag + k0 + 4);
        float4 a2 = *(const float4*)(Ag + k0 + 8);
        float4 a3 = *(const float4*)(Ag + k0 + 12);
        float4 b0 = *(const float4*)(Bg + k0);
        float4 b1 = *(const float4*)(Bg + k0 + 4);
        float4 b2 = *(const float4*)(Bg + k0 + 8);
        float4 b3 = *(const float4*)(Bg + k0 + 12);
        short8v h, l;
        split8(a0, a1, h, l);
        *(short8v*)pAh = h;  *(short8v*)pAl = l;
        split8(a2, a3, h, l);
        *(short8v*)(pAh + 8) = h;  *(short8v*)(pAl + 8) = l;
        split8(b0, b1, h, l);
        *(short8v*)pBh = h;  *(short8v*)pBl = l;
        split8(b2, b3, h, l);
        *(short8v*)(pBh + 8) = h;  *(short8v*)(pBl + 8) = l;
        __syncthreads();

        short8v afh[4], afl[4], bfh[4], bfl[4];
        #pragma unroll
        for (int fi = 0; fi < 4; ++fi) {
            const int ar = wr * 64 + fi * 16 + fr;
            afh[fi] = *(const short8v*)&Ah[ar * 40 + fq * 8];
            afl[fi] = *(const short8v*)&Al[ar * 40 + fq * 8];
        }
        #pragma unroll
        for (int bj = 0; bj < 4; ++bj) {
            const int br = wc * 64 + bj * 16 + fr;
            bfh[bj] = *(const short8v*)&Bh[br * 40 + fq * 8];
            bfl[bj] = *(const short8v*)&Bl[br * 40 + fq * 8];
        }
        #pragma unroll
        for (int fi = 0; fi < 4; ++fi) {
            #pragma unroll
            for (int bj = 0; bj < 4; ++bj) {
                acc[fi][bj] = __builtin_amdgcn_mfma_f32_16x16x32_bf16(
                    afh[fi], bfh[bj], acc[fi][bj], 0, 0, 0);
                acc[fi][bj] = __builtin_amdgcn_mfma_f32_16x16x32_bf16(
                    afh[fi], bfl[bj], acc[fi][bj], 0, 0, 0);
                acc[fi][bj] = __builtin_amdgcn_mfma_f32_16x16x32_bf16(
                    afl[fi], bfh[bj], acc[fi][bj], 0, 0, 0);
            }
        }
        __syncthreads();
    }

    #pragma unroll
    for (int fi = 0; fi < 4; ++fi) {
        #pragma unroll
        for (int bj = 0; bj < 4; ++bj) {
            const int r = m0 + wr * 64 + fi * 16 + fq * 4;
            const int c = ncol + wc * 64 + bj * 16 + fr;
            const float bv_ = bias[n0 - ncol + c];
            #pragma unroll
            for (int j = 0; j < 4; ++j)
                Cw[(size_t)(r + j) * 1024 + c] = acc[fi][bj][j] + bv_;
        }
    }
}

// ---------------------------------------------------------------------------
// K pre-split into B-frag-ready layout: Kth/Ktl [bh][2048 t][32 r] bf16.
// ---------------------------------------------------------------------------
__global__ __launch_bounds__(256) void kt_prep(
    const float* __restrict__ Yqk,
    short* __restrict__ Kth, short* __restrict__ Ktl)
{
    const int bh = blockIdx.x;
    const int b = bh >> 4, h = bh & 15;
    const int t0 = blockIdx.y * 128;
    const int tid = threadIdx.x;
    const int tl = tid >> 1, half = tid & 1;
    const float* src = Yqk + (size_t)(b * SEQ + t0 + tl) * 1024 + 512 + h * 32 + half * 16;
    short8v h0, l0, h1, l1;
    split8(((const float4*)src)[0], ((const float4*)src)[1], h0, l0);
    split8(((const float4*)src)[2], ((const float4*)src)[3], h1, l1);
    short* oh = Kth + ((size_t)bh * 2048 + t0 + tl) * 32 + half * 16;
    short* ol = Ktl + ((size_t)bh * 2048 + t0 + tl) * 32 + half * 16;
    *(short8v*)oh = h0;  *(short8v*)(oh + 8) = h1;
    *(short8v*)ol = l0;  *(short8v*)(ol + 8) = l1;
}

// ---------------------------------------------------------------------------
// V transpose + bf16-rn: Vtmp[4096][1024] -> Vbf [bh][64 d][2048 t]
// ---------------------------------------------------------------------------
__global__ __launch_bounds__(256) void vt_prep(
    const float* __restrict__ Vtmp, short* __restrict__ Vbf)
{
    __shared__ float t[64][68];
    const int bh = blockIdx.x;
    const int b = bh >> 4, h = bh & 15;
    const int t0 = blockIdx.y * 64;
    const int tid = threadIdx.x;
    {
        const int tl = tid >> 2, sg = tid & 3;
        const float* vp = Vtmp + (size_t)(b * SEQ + t0 + tl) * 1024 + h * 64 + sg * 16;
        #pragma unroll
        for (int i = 0; i < 4; ++i)
            *(float4*)&t[tl][sg * 16 + i * 4] = *(const float4*)(vp + i * 4);
    }
    __syncthreads();
    {
        const int d = tid >> 2, sg = tid & 3;
        short8v h0, h1;
        #pragma unroll
        for (int i = 0; i < 8; ++i) {
            h0[i] = (short)f2bf_rn(t[sg * 16 + i][d]);
            h1[i] = (short)f2bf_rn(t[sg * 16 + 8 + i][d]);
        }
        short* oh = Vbf + ((size_t)bh * 64 + d) * 2048 + t0 + sg * 16;
        *(short8v*)oh = h0;  *(short8v*)(oh + 8) = h1;
    }
}

// ---------------------------------------------------------------------------
// MFMA flash attention v2: ZERO barriers. K/V fragments are direct 16-B
// global loads from pre-split layouts (L2-resident); P round-trips through
// wave-private LDS only. All 16 loads issue at iteration top so V latency
// hides under QK+softmax. Waves fully independent.
// P_LD = 68: fq-group bank stride = 8 -> conflict-free P stores.
// ---------------------------------------------------------------------------
#define P_LD  68
#define MASKVAL (-1e30f)

__global__ __launch_bounds__(256, 2) void flash_mfma(
    const float* __restrict__ Yqk,   // [4096][1024]: q_lr(512) | k_lr(512)
    const short* __restrict__ Kth, const short* __restrict__ Ktl,
    const short* __restrict__ Vbf,   // [32][64][2048]
    float* __restrict__ O)           // [4096][1024] (B,T,H,Dh)
{
    const float scale = 0.1767766952966369f;  // 1/sqrt(32)
    const int bh = blockIdx.x;
    const int b = bh >> 4, h = bh & 15;
    const int qt = 31 - blockIdx.y;            // LPT
    const int tid = threadIdx.x;
    const int w = tid >> 6;
    const int lane = tid & 63;
    const int fr = lane & 15, fq = lane >> 4;

    __shared__ __align__(16) short Pl[4][16 * P_LD];
    short* Pw = &Pl[w][0];

    short8v aqh, aql;
    {
        const float* qp = Yqk + (size_t)(b * SEQ + qt * 64 + w * 16 + fr) * 1024
                          + h * 32 + fq * 8;
        split8(*(const float4*)qp, *(const float4*)(qp + 4), aqh, aql);
    }

    f32x4 acc0 = {0,0,0,0}, acc1 = {0,0,0,0}, acc2 = {0,0,0,0}, acc3 = {0,0,0,0};
    float m_[4], l_[4];
    #pragma unroll
    for (int r = 0; r < 4; ++r) { m_[r] = MASKVAL; l_[r] = 0.f; }

    const short* kb_h = Kth + (size_t)bh * 2048 * 32;
    const short* kb_l = Ktl + (size_t)bh * 2048 * 32;
    const short* vb   = Vbf + (size_t)bh * 64 * 2048;
    const int kidx = fr * 32 + fq * 8;          // within-tile K offset
    const int vrow = fr * 2048 + fq * 8;        // within-dt V offset

    for (int jt = 0; jt <= qt; ++jt) {
        // ---- all loads issue first (no barriers anywhere) ----
        const short* kp_h = kb_h + (size_t)jt * 64 * 32;
        const short* kp_l = kb_l + (size_t)jt * 64 * 32;
        short8v kh0 = *(const short8v*)&kp_h[kidx];
        short8v kh1 = *(const short8v*)&kp_h[kidx + 512];
        short8v kh2 = *(const short8v*)&kp_h[kidx + 1024];
        short8v kh3 = *(const short8v*)&kp_h[kidx + 1536];
        short8v kl0 = *(const short8v*)&kp_l[kidx];
        short8v kl1 = *(const short8v*)&kp_l[kidx + 512];
        short8v kl2 = *(const short8v*)&kp_l[kidx + 1024];
        short8v kl3 = *(const short8v*)&kp_l[kidx + 1536];
        const short* vp = vb + vrow + jt * 64;
        short8v v00 = *(const short8v*)&vp[0];
        short8v v01 = *(const short8v*)&vp[32];
        short8v v10 = *(const short8v*)&vp[16 * 2048];
        short8v v11 = *(const short8v*)&vp[16 * 2048 + 32];
        short8v v20 = *(const short8v*)&vp[32 * 2048];
        short8v v21 = *(const short8v*)&vp[32 * 2048 + 32];
        short8v v30 = *(const short8v*)&vp[48 * 2048];
        short8v v31 = *(const short8v*)&vp[48 * 2048 + 32];

        // ---- S = Q K^T (split-bf16) ----
        f32x4 s0 = {0,0,0,0}, s1 = {0,0,0,0}, s2 = {0,0,0,0}, s3 = {0,0,0,0};
        s0 = __builtin_amdgcn_mfma_f32_16x16x32_bf16(aqh, kh0, s0, 0, 0, 0);
        s0 = __builtin_amdgcn_mfma_f32_16x16x32_bf16(aqh, kl0, s0, 0, 0, 0);
        s0 = __builtin_amdgcn_mfma_f32_16x16x32_bf16(aql, kh0, s0, 0, 0, 0);
        s1 = __builtin_amdgcn_mfma_f32_16x16x32_bf16(aqh, kh1, s1, 0, 0, 0);
        s1 = __builtin_amdgcn_mfma_f32_16x16x32_bf16(aqh, kl1, s1, 0, 0, 0);
        s1 = __builtin_amdgcn_mfma_f32_16x16x32_bf16(aql, kh1, s1, 0, 0, 0);
        s2 = __builtin_amdgcn_mfma_f32_16x16x32_bf16(aqh, kh2, s2, 0, 0, 0);
        s2 = __builtin_amdgcn_mfma_f32_16x16x32_bf16(aqh, kl2, s2, 0, 0, 0);
        s2 = __builtin_amdgcn_mfma_f32_16x16x32_bf16(aql, kh2, s2, 0, 0, 0);
        s3 = __builtin_amdgcn_mfma_f32_16x16x32_bf16(aqh, kh3, s3, 0, 0, 0);
        s3 = __builtin_amdgcn_mfma_f32_16x16x32_bf16(aqh, kl3, s3, 0, 0, 0);
        s3 = __builtin_amdgcn_mfma_f32_16x16x32_bf16(aql, kh3, s3, 0, 0, 0);

        s0 *= scale; s1 *= scale; s2 *= scale; s3 *= scale;

        if (jt == qt) {
            #pragma unroll
            for (int r = 0; r < 4; ++r) {
                const int q_l = w * 16 + fq * 4 + r;
                s0[r] = (fr      <= q_l) ? s0[r] : MASKVAL;
                s1[r] = (16 + fr <= q_l) ? s1[r] : MASKVAL;
                s2[r] = (32 + fr <= q_l) ? s2[r] : MASKVAL;
                s3[r] = (48 + fr <= q_l) ? s3[r] : MASKVAL;
            }
        }

        // ---- online softmax (per q-row, 16-lane shfl groups) ----
        float al[4];
        #pragma unroll
        for (int r = 0; r < 4; ++r) {
            float mt = fmaxf(fmaxf(s0[r], s1[r]), fmaxf(s2[r], s3[r]));
            mt = fmaxf(mt, __shfl_xor(mt, 1));
            mt = fmaxf(mt, __shfl_xor(mt, 2));
            mt = fmaxf(mt, __shfl_xor(mt, 4));
            mt = fmaxf(mt, __shfl_xor(mt, 8));
            const float mnew = fmaxf(m_[r], mt);
            al[r] = __expf(m_[r] - mnew);
            m_[r] = mnew;
            s0[r] = __expf(s0[r] - mnew);
            s1[r] = __expf(s1[r] - mnew);
            s2[r] = __expf(s2[r] - mnew);
            s3[r] = __expf(s3[r] - mnew);
            float ps = s0[r] + s1[r] + s2[r] + s3[r];
            ps += __shfl_xor(ps, 1);
            ps += __shfl_xor(ps, 2);
            ps += __shfl_xor(ps, 4);
            ps += __shfl_xor(ps, 8);
            l_[r] = l_[r] * al[r] + ps;
        }

        // ---- P -> wave-private LDS (bf16-rn), then A-frag read ----
        #pragma unroll
        for (int r = 0; r < 4; ++r) {
            const int prow = fq * 4 + r;
            Pw[prow * P_LD +      fr] = (short)f2bf_rn(s0[r]);
            Pw[prow * P_LD + 16 + fr] = (short)f2bf_rn(s1[r]);
            Pw[prow * P_LD + 32 + fr] = (short)f2bf_rn(s2[r]);
            Pw[prow * P_LD + 48 + fr] = (short)f2bf_rn(s3[r]);
        }
        #pragma unroll
        for (int r = 0; r < 4; ++r) {
            acc0[r] *= al[r]; acc1[r] *= al[r];
            acc2[r] *= al[r]; acc3[r] *= al[r];
        }
        short8v pa0 = *(const short8v*)&Pw[fr * P_LD + fq * 8];
        short8v pa1 = *(const short8v*)&Pw[fr * P_LD + 32 + fq * 8];

        // ---- PV (V bf16-rn, single term) ----
        acc0 = __builtin_amdgcn_mfma_f32_16x16x32_bf16(pa0, v00, acc0, 0, 0, 0);
        acc0 = __builtin_amdgcn_mfma_f32_16x16x32_bf16(pa1, v01, acc0, 0, 0, 0);
        acc1 = __builtin_amdgcn_mfma_f32_16x16x32_bf16(pa0, v10, acc1, 0, 0, 0);
        acc1 = __builtin_amdgcn_mfma_f32_16x16x32_bf16(pa1, v11, acc1, 0, 0, 0);
        acc2 = __builtin_amdgcn_mfma_f32_16x16x32_bf16(pa0, v20, acc2, 0, 0, 0);
        acc2 = __builtin_amdgcn_mfma_f32_16x16x32_bf16(pa1, v21, acc2, 0, 0, 0);
        acc3 = __builtin_amdgcn_mfma_f32_16x16x32_bf16(pa0, v30, acc3, 0, 0, 0);
        acc3 = __builtin_amdgcn_mfma_f32_16x16x32_bf16(pa1, v31, acc3, 0, 0, 0);
    }

    #pragma unroll
    for (int r = 0; r < 4; ++r) {
        const float inv = 1.f / l_[r];
        const int trow = qt * 64 + w * 16 + fq * 4 + r;
        float* op = O + (size_t)(b * SEQ + trow) * 1024 + h * 64;
        op[     fr] = acc0[r] * inv;
        op[16 + fr] = acc1[r] * inv;
        op[32 + fr] = acc2[r] * inv;
        op[48 + fr] = acc3[r] * inv;
    }
}

// ---------------------------------------------------------------------------
extern "C" void kernel_launch(void* const* d_in, const int* in_sizes, int n_in,
                              void* d_out, int out_size, void* d_ws, size_t ws_size,
                              hipStream_t stream)
{
    const float* x      = (const float*)d_in[0];
    const float* Wq     = (const float*)d_in[1];
    const float* bq     = (const float*)d_in[2];
    const float* Wk     = (const float*)d_in[3];
    const float* bk     = (const float*)d_in[4];
    const float* Wv     = (const float*)d_in[5];
    const float* bv     = (const float*)d_in[6];
    const float* Wo     = (const float*)d_in[7];
    const float* bo     = (const float*)d_in[8];
    const float* Wq_lsr = (const float*)d_in[9];
    const float* Wk_lsr = (const float*)d_in[10];
    float* out = (float*)d_out;

    // workspace (floats/shorts), ~56 MB
    float* ws     = (float*)d_ws;
    float* Wcat_t = ws;                                    // 2M f (8 MB)
    float* bcat   = Wcat_t + (size_t)2048 * 1024;          // 2048
    float* Yqk    = bcat + 2048;                           // 4M f (16 MB)
    float* Vtmp   = Yqk + (size_t)M_TOT * 1024;            // 4M f (16 MB)
    short* Vbf    = (short*)(Vtmp + (size_t)M_TOT * 1024); // 4M s (8 MB)
    short* Kth    = Vbf + (size_t)32 * 64 * 2048;          // 2M s (4 MB)
    short* Ktl    = Kth + (size_t)32 * 2048 * 32;          // 2M s (4 MB)
    float* Weff_tmp = (float*)Vbf;   // alias: dead before vt_prep writes Vbf
    float* Oacc   = Vtmp;            // alias: fp32 V dead after vt_prep
    float* Wo_t   = Wcat_t;          // alias: Wcat_t dead after proj gemm

    eff_weight_kernel<<<2048, 256, 0, stream>>>(Wq, Wq_lsr, Weff_tmp, 0);
    eff_weight_kernel<<<2048, 256, 0, stream>>>(Wk, Wk_lsr, Weff_tmp, 512);
    eff_bias_kernel<<<8, 256, 0, stream>>>(bq, Wq_lsr, bk, Wk_lsr, bv, bcat);

    transpose1024<<<dim3(16, 16), 256, 0, stream>>>(Weff_tmp, Wcat_t);
    transpose1024<<<dim3(16, 16), 256, 0, stream>>>(Wv, Wcat_t + (size_t)1024 * 1024);

    // [Yqk | Vtmp] = x @ [Wq_eff|Wk_eff|Wv] + bcat
    gemm_bt_split<<<dim3(16, 32), 256, 0, stream>>>(
        x, Wcat_t, bcat, Yqk, Vtmp, 1024);

    vt_prep<<<dim3(32, 32), 256, 0, stream>>>(Vtmp, Vbf);
    kt_prep<<<dim3(32, 16), 256, 0, stream>>>(Yqk, Kth, Ktl);

    transpose1024<<<dim3(16, 16), 256, 0, stream>>>(Wo, Wo_t);

    flash_mfma<<<dim3(32, 32), 256, 0, stream>>>(Yqk, Kth, Ktl, Vbf, Oacc);

    // out = Oacc @ Wo + bo
    gemm_bt_split<<<dim3(8, 32), 256, 0, stream>>>(
        Oacc, Wo_t, bo, out, out, 1 << 30);
}